// Round 4
// baseline (638.594 us; speedup 1.0000x reference)
//
#include <hip/hip_runtime.h>
#include <math.h>

// kmeans assignment: X [N,D] f32, Phi [C,D] f32 -> argmin_c ||x - phi_c||^2, indices as INT32
// (harness reads d_out as np.int32 for int32-output references — round-2 failure was float-bit
// patterns being reinterpreted as int32, absmax 1.13e9 == bits of ~255.0f).
// N*C*D = 12.8G fma -> f32 VALU-bound (~163us floor at 157 TF). Phi read via wave-uniform
// scalar loads (SGPR broadcast); x row held in VGPRs; 4 explicit accumulator chains for ILP.
#define NPTS 1000000
#define DIM 50
#define NC 256

__global__ void __launch_bounds__(256) p2_prep(const float* __restrict__ Phi,
                                               float* __restrict__ p2) {
    int c = threadIdx.x;  // exactly NC threads
    const float* p = Phi + c * DIM;
    float s = 0.f;
#pragma unroll
    for (int d = 0; d < DIM; ++d) s = fmaf(p[d], p[d], s);
    p2[c] = s;
}

__global__ void __launch_bounds__(256) assign_kernel(const float* __restrict__ X,
                                                     const float* __restrict__ Phi,
                                                     const float* __restrict__ p2,
                                                     int* __restrict__ out) {
    int row = blockIdx.x * 256 + threadIdx.x;
    if (row >= NPTS) return;

    // Load this thread's x row (50 f32). Rows are 200B apart -> 8B aligned, float2 loads.
    float x[DIM];
    const float2* xr = reinterpret_cast<const float2*>(X) + (size_t)row * (DIM / 2);
#pragma unroll
    for (int i = 0; i < DIM / 2; ++i) {
        float2 t = xr[i];
        x[2 * i]     = t.x;
        x[2 * i + 1] = t.y;
    }

    float x2 = 0.f;
#pragma unroll
    for (int d = 0; d < DIM; ++d) x2 = fmaf(x[d], x[d], x2);

    float best = INFINITY;
    int bidx = 0;
    // Phi accesses are wave-uniform -> s_load (SGPR broadcast); inner loop is pure
    // v_fma_f32 with one scalar operand. 4 centroids/iter = 4 independent fma chains.
    for (int c = 0; c < NC; c += 4) {
        const float* prow = Phi + c * DIM;
        float a0 = 0.f, a1 = 0.f, a2 = 0.f, a3 = 0.f;
#pragma unroll
        for (int d = 0; d < DIM; ++d) {
            float xd = x[d];
            a0 = fmaf(xd, prow[d], a0);
            a1 = fmaf(xd, prow[DIM + d], a1);
            a2 = fmaf(xd, prow[2 * DIM + d], a2);
            a3 = fmaf(xd, prow[3 * DIM + d], a3);
        }
        // Match reference rounding order: (x2 + p2) - 2*dot
        float d0 = (x2 + p2[c])     - 2.0f * a0;
        float d1 = (x2 + p2[c + 1]) - 2.0f * a1;
        float d2 = (x2 + p2[c + 2]) - 2.0f * a2;
        float d3 = (x2 + p2[c + 3]) - 2.0f * a3;
        // Strict < keeps the first minimum (jnp.argmin tie rule); sequential
        // compares preserve ascending-index preference.
        if (d0 < best) { best = d0; bidx = c; }
        if (d1 < best) { best = d1; bidx = c + 1; }
        if (d2 < best) { best = d2; bidx = c + 2; }
        if (d3 < best) { best = d3; bidx = c + 3; }
    }
    out[row] = bidx;  // int32 — harness reads d_out as np.int32
}

extern "C" void kernel_launch(void* const* d_in, const int* in_sizes, int n_in,
                              void* d_out, int out_size, void* d_ws, size_t ws_size,
                              hipStream_t stream) {
    const float* X   = (const float*)d_in[0];
    const float* Phi = (const float*)d_in[1];
    int* out  = (int*)d_out;
    float* p2 = (float*)d_ws;  // 256 floats of scratch

    p2_prep<<<1, NC, 0, stream>>>(Phi, p2);
    int nblk = (NPTS + 255) / 256;
    assign_kernel<<<nblk, 256, 0, stream>>>(X, Phi, p2, out);
}

// Round 10
// 521.889 us; speedup vs baseline: 1.2236x; 1.2236x over previous
//
#include <hip/hip_runtime.h>
#include <math.h>

// kmeans assign = GEMM X[1M x 50] . Phi^T[50 x 256] with fused argmin epilogue.
// f32 scalar is VALU-capped (~163us floor; measured 483us w/ VGPR=32 spill fiasco).
// MFMA path: split f32 -> bf16 hi+lo, 3 products (hh, hl, lh) ~ 98 GFLOP @ ~2.1PF ~ 47us.
// Score error <= ~1.5e-3 (dropped lo*lo); rows with margin < TAU=0.05 are re-solved
// exactly in-wave with the sequential-fma f32 expression that scored absmax=0 in
// round 4 (same first-min tie-break as jnp.argmin).
#define NPTS 1000000
#define DIM 50
#define NC 256
#define TAU 0.05f

typedef short bf16x8 __attribute__((ext_vector_type(8)));   // 8 bf16 (4 VGPRs)
typedef float f32x4 __attribute__((ext_vector_type(4)));    // 4 fp32 acc

__device__ __forceinline__ short f2bf(float f) {            // f32 -> bf16 RN-even
    unsigned u = __builtin_bit_cast(unsigned, f);
    unsigned r = (u + 0x7FFFu + ((u >> 16) & 1u)) >> 16;
    return (short)r;
}
__device__ __forceinline__ float bf2f(short h) {
    unsigned u = ((unsigned)(unsigned short)h) << 16;
    return __builtin_bit_cast(float, u);
}
__device__ __forceinline__ void cvt8(const float* v, bf16x8& hi, bf16x8& lo) {
#pragma unroll
    for (int j = 0; j < 8; ++j) {
        short h = f2bf(v[j]);
        hi[j] = h;
        lo[j] = f2bf(v[j] - bf2f(h));
    }
}

// ws layout: [0, 64KB) = Phi bf16 hi/lo fragments [ct(16)][ks(2)][split(2)][lane(64)][8 shorts]
//            [64KB, 64KB+1KB) = p2[256] f32
__global__ void __launch_bounds__(256) prep_kernel(const float* __restrict__ Phi,
                                                   short* __restrict__ frag,
                                                   float* __restrict__ p2) {
    int tid = threadIdx.x;
    // p2
    {
        const float* p = Phi + tid * DIM;
        float s = 0.f;
#pragma unroll
        for (int d = 0; d < DIM; ++d) s = fmaf(p[d], p[d], s);
        p2[tid] = s;
    }
    // fragments: 4096 lane-frags, 16 per thread
    for (int it = tid; it < 4096; it += 256) {
        int lane = it & 63;
        int rest = it >> 6;          // 0..63
        int split = rest & 1;
        int ks = (rest >> 1) & 1;
        int ct = rest >> 2;          // 0..15
        int col = lane & 15;
        int kb = ks * 32 + ((lane >> 4) << 3);
        const float* pr = Phi + (ct * 16 + col) * DIM;
        short* dst = frag + (size_t)it * 8;
#pragma unroll
        for (int j = 0; j < 8; ++j) {
            int k = kb + j;
            float v = (k < DIM) ? pr[k] : 0.f;
            short h = f2bf(v);
            dst[j] = (split == 0) ? h : f2bf(v - bf2f(h));
        }
    }
}

// Exact f32 rescreen for one row: identical math/tie-break to the round-4 scalar kernel.
__device__ void exact_row(const float* __restrict__ X, const float* __restrict__ Phi,
                          const float* __restrict__ p2, int* __restrict__ out, int row) {
    int lane = threadIdx.x & 63;
    const float* xr = X + (size_t)row * DIM;
    float x2 = 0.f;
#pragma unroll
    for (int d = 0; d < DIM; ++d) x2 = fmaf(xr[d], xr[d], x2);
    float best = INFINITY;
    int bi = 0;
    for (int i = 0; i < 4; ++i) {
        int c = lane * 4 + i;                 // within-lane ascending c; strict <
        const float* pr = Phi + c * DIM;
        float a = 0.f;
#pragma unroll
        for (int d = 0; d < DIM; ++d) a = fmaf(xr[d], pr[d], a);
        float sc = (x2 + p2[c]) - 2.0f * a;   // reference rounding order
        if (sc < best) { best = sc; bi = c; }
    }
#pragma unroll
    for (int m = 1; m < 64; m <<= 1) {        // cross-lane: lower idx wins ties
        float ob = __shfl_xor(best, m);
        int oi = __shfl_xor(bi, m);
        if (ob < best || (ob == best && oi < bi)) { best = ob; bi = oi; }
    }
    if (lane == 0) out[row] = bi;
}

__global__ void __launch_bounds__(256, 2) assign_kernel(const float* __restrict__ X,
                                                        const float* __restrict__ Phi,
                                                        const bf16x8* __restrict__ Bf,
                                                        const float* __restrict__ p2,
                                                        int* __restrict__ out) {
    int lane = threadIdx.x & 63;
    int t = blockIdx.x * 4 + (threadIdx.x >> 6);   // wave tile id: 64 rows each
    if (t >= NPTS / 64) return;
    int tbase = t * 64;
    int colRow = lane & 15;   // A: row-within-16; C: col-within-16
    int kgrp = lane >> 4;

    // ---- Load + split A fragments: 4 M-subtiles x 2 k-steps (K padded 50->64) ----
    bf16x8 Ahi[4][2], Alo[4][2];
#pragma unroll
    for (int mr = 0; mr < 4; ++mr) {
        const float* xp = X + (size_t)(tbase + mr * 16 + colRow) * DIM;
        {   // ks=0: k = kgrp*8 + j <= 31 < 50, unconditional. Row stride 200B -> only 8B-aligned.
            float v[8];
            const float2* q = (const float2*)(xp + (kgrp << 3));
#pragma unroll
            for (int h = 0; h < 4; ++h) { float2 e = q[h]; v[2 * h] = e.x; v[2 * h + 1] = e.y; }
            cvt8(v, Ahi[mr][0], Alo[mr][0]);
        }
        {   // ks=1: k = 32 + kgrp*8 + j, predicated (pad 50..63 with 0)
            float v[8];
            int kb = 32 + (kgrp << 3);
#pragma unroll
            for (int j = 0; j < 8; ++j) v[j] = (kb + j < DIM) ? xp[kb + j] : 0.f;
            cvt8(v, Ahi[mr][1], Alo[mr][1]);
        }
    }

    // ---- Running argmin state per (mr, reg) slot = one row each ----
    float best[4][4], sec[4][4];
    int bidx[4][4];
#pragma unroll
    for (int mr = 0; mr < 4; ++mr)
#pragma unroll
        for (int r = 0; r < 4; ++r) { best[mr][r] = INFINITY; sec[mr][r] = INFINITY; bidx[mr][r] = 0; }

    // ---- Main loop over 16 col-tiles ----
#pragma unroll 2
    for (int ct = 0; ct < 16; ++ct) {
        bf16x8 b0h = Bf[((ct * 2 + 0) * 2 + 0) * 64 + lane];
        bf16x8 b0l = Bf[((ct * 2 + 0) * 2 + 1) * 64 + lane];
        bf16x8 b1h = Bf[((ct * 2 + 1) * 2 + 0) * 64 + lane];
        bf16x8 b1l = Bf[((ct * 2 + 1) * 2 + 1) * 64 + lane];
        float p2v = p2[ct * 16 + colRow];
        int idx = ct * 16 + colRow;
#pragma unroll
        for (int mr = 0; mr < 4; ++mr) {
            f32x4 acc = {0.f, 0.f, 0.f, 0.f};
            acc = __builtin_amdgcn_mfma_f32_16x16x32_bf16(Alo[mr][0], b0h, acc, 0, 0, 0);
            acc = __builtin_amdgcn_mfma_f32_16x16x32_bf16(Ahi[mr][0], b0l, acc, 0, 0, 0);
            acc = __builtin_amdgcn_mfma_f32_16x16x32_bf16(Ahi[mr][0], b0h, acc, 0, 0, 0);
            acc = __builtin_amdgcn_mfma_f32_16x16x32_bf16(Alo[mr][1], b1h, acc, 0, 0, 0);
            acc = __builtin_amdgcn_mfma_f32_16x16x32_bf16(Ahi[mr][1], b1l, acc, 0, 0, 0);
            acc = __builtin_amdgcn_mfma_f32_16x16x32_bf16(Ahi[mr][1], b1h, acc, 0, 0, 0);
#pragma unroll
            for (int r = 0; r < 4; ++r) {
                float sc = fmaf(-2.0f, acc[r], p2v);   // x2 const per row: dropped
                if (sc < best[mr][r]) { sec[mr][r] = best[mr][r]; best[mr][r] = sc; bidx[mr][r] = idx; }
                else if (sc < sec[mr][r]) { sec[mr][r] = sc; }
            }
        }
    }

    // ---- Epilogue: reduce over the 16-lane row group; store or rescreen ----
#pragma unroll
    for (int mr = 0; mr < 4; ++mr) {
#pragma unroll
        for (int r = 0; r < 4; ++r) {
            float b = best[mr][r], s = sec[mr][r];
            int bi = bidx[mr][r];
#pragma unroll
            for (int m = 1; m <= 8; m <<= 1) {
                float ob = __shfl_xor(b, m);
                float os = __shfl_xor(s, m);
                int oi = __shfl_xor(bi, m);
                float ns = fminf(fmaxf(b, ob), fminf(s, os));  // exact 2nd-min of union
                if (ob < b || (ob == b && oi < bi)) { b = ob; bi = oi; }
                s = ns;
            }
            bool flag = (s - b) < TAU;   // uniform across the 16-lane group
            if ((lane & 15) == 0 && !flag)
                out[tbase + mr * 16 + (lane >> 4) * 4 + r] = bi;
            // Exact rescreen for flagged rows (whole wave cooperates; ~0.9% of rows)
            unsigned long long mb = __ballot(flag) & 0x0001000100010001ULL;
            while (mb) {
                int g = __builtin_ctzll(mb) >> 4;
                mb &= mb - 1;
                exact_row(X, Phi, p2, out, tbase + mr * 16 + g * 4 + r);
            }
        }
    }
}

extern "C" void kernel_launch(void* const* d_in, const int* in_sizes, int n_in,
                              void* d_out, int out_size, void* d_ws, size_t ws_size,
                              hipStream_t stream) {
    const float* X   = (const float*)d_in[0];
    const float* Phi = (const float*)d_in[1];
    int* out = (int*)d_out;
    short* frag = (short*)d_ws;                        // 64 KB
    float* p2   = (float*)((char*)d_ws + 65536);       // 1 KB

    prep_kernel<<<1, 256, 0, stream>>>(Phi, frag, p2);
    int ntiles = NPTS / 64;                            // 15625
    int nblk = (ntiles + 3) / 4;                       // 3907
    assign_kernel<<<nblk, 256, 0, stream>>>(X, Phi, (const bf16x8*)frag, p2, out);
}

// Round 11
// 438.991 us; speedup vs baseline: 1.4547x; 1.1888x over previous
//
#include <hip/hip_runtime.h>
#include <math.h>

// kmeans assign = GEMM X[1M x 50] . Phi^T[50 x 256] with fused argmin epilogue.
// R10 (validated, absmax=0): 325us, MfmaUtil 12.5%, VALUBusy 35%, Occ 20% -> latency-bound
// on per-ct global B-frag reloads (1GB @ ~200cy) at thin occupancy.
// R11: B-frags staged in LDS once per block (64KB); 512-thr blocks, lb(512,4) caps VGPR<=128
// (4 waves/SIMD, 2 blocks/CU); MR=2 (32 rows/wave) to fit regs; clamped float2 ks=1 A-loads.
// Math/epilogue/rescreen identical to the validated R10 kernel.
#define NPTS 1000000
#define DIM 50
#define NC 256
#define TAU 0.05f
#define MR 2
#define NTILES (NPTS / (MR * 16))   // 31250 wave-tiles of 32 rows

typedef short bf16x8 __attribute__((ext_vector_type(8)));   // 8 bf16 (4 VGPRs)
typedef float f32x4 __attribute__((ext_vector_type(4)));    // 4 fp32 acc

__device__ __forceinline__ short f2bf(float f) {            // f32 -> bf16 RN-even
    unsigned u = __builtin_bit_cast(unsigned, f);
    unsigned r = (u + 0x7FFFu + ((u >> 16) & 1u)) >> 16;
    return (short)r;
}
__device__ __forceinline__ float bf2f(short h) {
    unsigned u = ((unsigned)(unsigned short)h) << 16;
    return __builtin_bit_cast(float, u);
}
__device__ __forceinline__ void cvt8(const float* v, bf16x8& hi, bf16x8& lo) {
#pragma unroll
    for (int j = 0; j < 8; ++j) {
        short h = f2bf(v[j]);
        hi[j] = h;
        lo[j] = f2bf(v[j] - bf2f(h));
    }
}

// ws layout: [0, 64KB) = Phi bf16 hi/lo fragments [ct(16)][ks(2)][split(2)][lane(64)][8 shorts]
//            [64KB, 64KB+1KB) = p2[256] f32
__global__ void __launch_bounds__(256) prep_kernel(const float* __restrict__ Phi,
                                                   short* __restrict__ frag,
                                                   float* __restrict__ p2) {
    int tid = threadIdx.x;
    {
        const float* p = Phi + tid * DIM;
        float s = 0.f;
#pragma unroll
        for (int d = 0; d < DIM; ++d) s = fmaf(p[d], p[d], s);
        p2[tid] = s;
    }
    for (int it = tid; it < 4096; it += 256) {
        int lane = it & 63;
        int rest = it >> 6;
        int split = rest & 1;
        int ks = (rest >> 1) & 1;
        int ct = rest >> 2;
        int col = lane & 15;
        int kb = ks * 32 + ((lane >> 4) << 3);
        const float* pr = Phi + (ct * 16 + col) * DIM;
        short* dst = frag + (size_t)it * 8;
#pragma unroll
        for (int j = 0; j < 8; ++j) {
            int k = kb + j;
            float v = (k < DIM) ? pr[k] : 0.f;
            short h = f2bf(v);
            dst[j] = (split == 0) ? h : f2bf(v - bf2f(h));
        }
    }
}

// Exact f32 rescreen for one row: identical math/tie-break to the validated scalar kernel.
__device__ void exact_row(const float* __restrict__ X, const float* __restrict__ Phi,
                          const float* __restrict__ p2, int* __restrict__ out, int row) {
    int lane = threadIdx.x & 63;
    const float* xr = X + (size_t)row * DIM;
    float x2 = 0.f;
#pragma unroll
    for (int d = 0; d < DIM; ++d) x2 = fmaf(xr[d], xr[d], x2);
    float best = INFINITY;
    int bi = 0;
    for (int i = 0; i < 4; ++i) {
        int c = lane * 4 + i;                 // within-lane ascending c; strict <
        const float* pr = Phi + c * DIM;
        float a = 0.f;
#pragma unroll
        for (int d = 0; d < DIM; ++d) a = fmaf(xr[d], pr[d], a);
        float sc = (x2 + p2[c]) - 2.0f * a;   // reference rounding order
        if (sc < best) { best = sc; bi = c; }
    }
#pragma unroll
    for (int m = 1; m < 64; m <<= 1) {        // cross-lane: lower idx wins ties
        float ob = __shfl_xor(best, m);
        int oi = __shfl_xor(bi, m);
        if (ob < best || (ob == best && oi < bi)) { best = ob; bi = oi; }
    }
    if (lane == 0) out[row] = bi;
}

__global__ void __launch_bounds__(512, 4) assign_kernel(const float* __restrict__ X,
                                                        const float* __restrict__ Phi,
                                                        const int4* __restrict__ BfI,
                                                        const float* __restrict__ p2,
                                                        int* __restrict__ out) {
    __shared__ int4 Bs[4096];   // exactly 64 KB: all 16ct x 2ks x 2split x 64lane frags

    // ---- Stage B fragments to LDS (all 512 threads; before any exit!) ----
#pragma unroll
    for (int j = 0; j < 8; ++j)
        Bs[threadIdx.x + j * 512] = BfI[threadIdx.x + j * 512];
    __syncthreads();

    int lane = threadIdx.x & 63;
    int wid = threadIdx.x >> 6;
    int t = blockIdx.x * 8 + wid;              // wave tile id: 32 rows each
    if (t >= NTILES) return;                   // after barrier: safe
    int tbase = t * (MR * 16);
    int colRow = lane & 15;                    // A: row-within-16; C: col-within-16
    int kgrp = lane >> 4;

    const bf16x8* Bsf = (const bf16x8*)Bs;

    // ---- Load + split A fragments: MR M-subtiles x 2 k-steps (K padded 50->64) ----
    bf16x8 Ahi[MR][2], Alo[MR][2];
#pragma unroll
    for (int mr = 0; mr < MR; ++mr) {
        const float* xp = X + (size_t)(tbase + mr * 16 + colRow) * DIM;
        {   // ks=0: k = kgrp*8 + 2h (+1) <= 31 < 50, unconditional float2
            float v[8];
            const float2* q = (const float2*)(xp + (kgrp << 3));
#pragma unroll
            for (int h = 0; h < 4; ++h) { float2 e = q[h]; v[2 * h] = e.x; v[2 * h + 1] = e.y; }
            cvt8(v, Ahi[mr][0], Alo[mr][0]);
        }
        {   // ks=1: o = 32+kgrp*8+2h; clamp load to row end, mask invalid (o>48)
            float v[8];
#pragma unroll
            for (int h = 0; h < 4; ++h) {
                int o = 32 + (kgrp << 3) + 2 * h;
                int oc = (o <= 48) ? o : 48;               // keep load in-row
                float2 e = *(const float2*)(xp + oc);
                bool valid = (o <= 48);                     // elems o,o+1 < 50
                v[2 * h]     = valid ? e.x : 0.f;
                v[2 * h + 1] = valid ? e.y : 0.f;
            }
            cvt8(v, Ahi[mr][1], Alo[mr][1]);
        }
    }

    // ---- Running argmin state per (mr, reg) slot = one row each ----
    float best[MR][4], sec[MR][4];
    int bidx[MR][4];
#pragma unroll
    for (int mr = 0; mr < MR; ++mr)
#pragma unroll
        for (int r = 0; r < 4; ++r) { best[mr][r] = INFINITY; sec[mr][r] = INFINITY; bidx[mr][r] = 0; }

    // ---- Main loop over 16 col-tiles; B from LDS ----
#pragma unroll 2
    for (int ct = 0; ct < 16; ++ct) {
        bf16x8 b0h = Bsf[((ct * 2 + 0) * 2 + 0) * 64 + lane];
        bf16x8 b0l = Bsf[((ct * 2 + 0) * 2 + 1) * 64 + lane];
        bf16x8 b1h = Bsf[((ct * 2 + 1) * 2 + 0) * 64 + lane];
        bf16x8 b1l = Bsf[((ct * 2 + 1) * 2 + 1) * 64 + lane];
        float p2v = p2[ct * 16 + colRow];
        int idx = ct * 16 + colRow;
#pragma unroll
        for (int mr = 0; mr < MR; ++mr) {
            f32x4 acc = {0.f, 0.f, 0.f, 0.f};
            acc = __builtin_amdgcn_mfma_f32_16x16x32_bf16(Alo[mr][0], b0h, acc, 0, 0, 0);
            acc = __builtin_amdgcn_mfma_f32_16x16x32_bf16(Ahi[mr][0], b0l, acc, 0, 0, 0);
            acc = __builtin_amdgcn_mfma_f32_16x16x32_bf16(Ahi[mr][0], b0h, acc, 0, 0, 0);
            acc = __builtin_amdgcn_mfma_f32_16x16x32_bf16(Alo[mr][1], b1h, acc, 0, 0, 0);
            acc = __builtin_amdgcn_mfma_f32_16x16x32_bf16(Ahi[mr][1], b1l, acc, 0, 0, 0);
            acc = __builtin_amdgcn_mfma_f32_16x16x32_bf16(Ahi[mr][1], b1h, acc, 0, 0, 0);
#pragma unroll
            for (int r = 0; r < 4; ++r) {
                float sc = fmaf(-2.0f, acc[r], p2v);   // x2 const per row: dropped
                if (sc < best[mr][r]) { sec[mr][r] = best[mr][r]; best[mr][r] = sc; bidx[mr][r] = idx; }
                else if (sc < sec[mr][r]) { sec[mr][r] = sc; }
            }
        }
    }

    // ---- Epilogue: reduce over the 16-lane row group; store or rescreen ----
#pragma unroll
    for (int mr = 0; mr < MR; ++mr) {
#pragma unroll
        for (int r = 0; r < 4; ++r) {
            float b = best[mr][r], s = sec[mr][r];
            int bi = bidx[mr][r];
#pragma unroll
            for (int m = 1; m <= 8; m <<= 1) {
                float ob = __shfl_xor(b, m);
                float os = __shfl_xor(s, m);
                int oi = __shfl_xor(bi, m);
                float ns = fminf(fmaxf(b, ob), fminf(s, os));  // exact 2nd-min of union
                if (ob < b || (ob == b && oi < bi)) { b = ob; bi = oi; }
                s = ns;
            }
            bool flag = (s - b) < TAU;   // uniform across the 16-lane group
            if ((lane & 15) == 0 && !flag)
                out[tbase + mr * 16 + (lane >> 4) * 4 + r] = bi;
            // Exact rescreen for flagged rows (whole wave cooperates; ~1% of rows)
            unsigned long long mb = __ballot(flag) & 0x0001000100010001ULL;
            while (mb) {
                int g = __builtin_ctzll(mb) >> 4;
                mb &= mb - 1;
                exact_row(X, Phi, p2, out, tbase + mr * 16 + g * 4 + r);
            }
        }
    }
}

extern "C" void kernel_launch(void* const* d_in, const int* in_sizes, int n_in,
                              void* d_out, int out_size, void* d_ws, size_t ws_size,
                              hipStream_t stream) {
    const float* X   = (const float*)d_in[0];
    const float* Phi = (const float*)d_in[1];
    int* out = (int*)d_out;
    short* frag = (short*)d_ws;                        // 64 KB
    float* p2   = (float*)((char*)d_ws + 65536);       // 1 KB

    prep_kernel<<<1, 256, 0, stream>>>(Phi, frag, p2);
    int nblk = (NTILES + 7) / 8;                       // 3907 blocks x 512 threads
    assign_kernel<<<nblk, 512, 0, stream>>>(X, Phi, (const int4*)frag, p2, out);
}